// Round 6
// baseline (651.354 us; speedup 1.0000x reference)
//
#include <hip/hip_runtime.h>
#include <hip/hip_bf16.h>

#define IRREPS 240
#define BNODES 20      // nodes per bucket
#define ROWPAD 256     // bf16 elems per stored row = 512 B

// ---- bucket histogram ----
__global__ void bucket_hist_kernel(const int* __restrict__ eidx, int* __restrict__ bcount,
                                   int n_edges) {
    int e = blockIdx.x * blockDim.x + threadIdx.x;
    if (e >= n_edges) return;
    int2 p = reinterpret_cast<const int2*>(eidx)[e];
    atomicAdd(&bcount[p.y / BNODES], 1);
}

// ---- exclusive scan over <=1024 buckets, one block ----
__global__ void bucket_scan_kernel(const int* __restrict__ bcount, int* __restrict__ boffset,
                                   int* __restrict__ bcursor, int nb) {
    __shared__ int part[1024];
    int t = threadIdx.x;
    int v = (t < nb) ? bcount[t] : 0;
    part[t] = v;
    __syncthreads();
    for (int off = 1; off < 1024; off <<= 1) {
        int u = (t >= off) ? part[t - off] : 0;
        __syncthreads();
        part[t] += u;
        __syncthreads();
    }
    if (t < nb) {
        int excl = part[t] - v;
        boffset[t] = excl;
        bcursor[t] = excl;
        if (t == nb - 1) boffset[nb] = part[t];
    }
}

// ---- phase A: stream msgs, weighted bf16 convert, append to bucket region ----
// One wave per edge (grid-stride). Planar pack: lane l carries elements
// {l, l+60, l+120, l+180} so phase B's LDS adds are stride-1 (conflict-free).
__global__ void bucket_scatter_kernel(const float* __restrict__ msgs,
                                      const int* __restrict__ eidx,
                                      const float* __restrict__ cutoff,
                                      int* __restrict__ bcursor,
                                      int* __restrict__ tgt_arr,
                                      __hip_bfloat16* __restrict__ perm,
                                      int n_edges) {
    int t = threadIdx.x;
    int w = t >> 6;
    int l = t & 63;
    int wave = blockIdx.x * 4 + w;
    int nwaves = gridDim.x * 4;

    for (int e = wave; e < n_edges; e += nwaves) {
        int tgt = eidx[2 * e + 1];
        float wt = cutoff[e];
        int pos = 0;
        if (l == 0) pos = atomicAdd(&bcursor[tgt / BNODES], 1);
        pos = __shfl(pos, 0);

        union { __hip_bfloat16 h[4]; uint2 u; } pk;
        if (l < 60) {
            const float* row = msgs + (size_t)e * IRREPS;
            pk.h[0] = __float2bfloat16(row[l]       * wt);
            pk.h[1] = __float2bfloat16(row[l + 60]  * wt);
            pk.h[2] = __float2bfloat16(row[l + 120] * wt);
            pk.h[3] = __float2bfloat16(row[l + 180] * wt);
        } else {
            pk.u = make_uint2(0u, 0u);
        }
        *reinterpret_cast<uint2*>(perm + (size_t)pos * ROWPAD + l * 4) = pk.u;
        if (l == 0) tgt_arr[pos] = tgt;
    }
}

// ---- phase B: per bucket, stream rows sequentially, LDS fp32 accumulate, fused linear ----
__global__ void bucket_reduce_linear_kernel(const __hip_bfloat16* __restrict__ perm,
                                            const int* __restrict__ tgt_arr,
                                            const int* __restrict__ boffset,
                                            const float* __restrict__ W0,
                                            const float* __restrict__ W1,
                                            const float* __restrict__ W2,
                                            float* __restrict__ out,
                                            int n_nodes) {
    __shared__ float s_agg[BNODES * IRREPS];

    int b = blockIdx.x;
    int t = threadIdx.x;
    int w = t >> 6;
    int l = t & 63;

    int bstart = boffset[b];
    int bend = boffset[b + 1];
    int nfirst = b * BNODES;

    for (int i = t; i < BNODES * IRREPS; i += 256) s_agg[i] = 0.f;
    __syncthreads();

    #pragma unroll 4
    for (int r = bstart + w; r < bend; r += 4) {
        int tgt = tgt_arr[r];           // wave-uniform broadcast load
        int local = tgt - nfirst;
        if (l < 60) {
            uint2 v = *reinterpret_cast<const uint2*>(perm + (size_t)r * ROWPAD + l * 4);
            float* dst = s_agg + local * IRREPS + l;
            atomicAdd(dst +   0, __uint_as_float(v.x << 16));
            atomicAdd(dst +  60, __uint_as_float(v.x & 0xffff0000u));
            atomicAdd(dst + 120, __uint_as_float(v.y << 16));
            atomicAdd(dst + 180, __uint_as_float(v.y & 0xffff0000u));
        }
    }
    __syncthreads();

    // fused equivariant linear from LDS accumulators
    for (int idx = t; idx < BNODES * IRREPS; idx += 256) {
        int node = idx / IRREPS;
        int col = idx - node * IRREPS;
        int gn = nfirst + node;
        if (gn >= n_nodes) break;
        const float* s = s_agg + node * IRREPS;
        float a = 0.f;
        float res;
        if (col < 64) {
            #pragma unroll 8
            for (int i = 0; i < 64; ++i) a += W0[col * 64 + i] * s[i];
            res = a * 0.125f;               // 1/sqrt(64)
        } else if (col < 160) {
            int rel = col - 64;
            int o = rel / 3, d = rel - o * 3;
            #pragma unroll 8
            for (int i = 0; i < 32; ++i) a += W1[o * 32 + i] * s[64 + i * 3 + d];
            res = a * 0.17677669529663687f; // 1/sqrt(32)
        } else {
            int rel = col - 160;
            int o = rel / 5, d = rel - o * 5;
            #pragma unroll
            for (int i = 0; i < 16; ++i) a += W2[o * 16 + i] * s[160 + i * 5 + d];
            res = a * 0.25f;                // 1/sqrt(16)
        }
        out[(size_t)gn * IRREPS + col] = res;
    }
}

extern "C" void kernel_launch(void* const* d_in, const int* in_sizes, int n_in,
                              void* d_out, int out_size, void* d_ws, size_t ws_size,
                              hipStream_t stream) {
    const float* msgs   = (const float*)d_in[0];
    const int*   eidx   = (const int*)d_in[1];
    const float* cutoff = (const float*)d_in[2];
    const float* W0     = (const float*)d_in[3];
    const float* W1     = (const float*)d_in[4];
    const float* W2     = (const float*)d_in[5];

    int n_edges = in_sizes[0] / IRREPS;
    int n_nodes = out_size / IRREPS;
    int nb = (n_nodes + BNODES - 1) / BNODES;   // 1000 (<=1024 required)

    // workspace layout
    int* bcount  = (int*)d_ws;          // [1024]
    int* boffset = bcount + 1024;       // [1025]
    int* bcursor = boffset + 1032;      // [1024]
    int* tgt_arr = bcursor + 1024;      // [n_edges]
    size_t intbytes = (size_t)(1024 + 1032 + 1024 + n_edges) * sizeof(int);
    size_t permoff = (intbytes + 511) & ~(size_t)511;
    __hip_bfloat16* perm = (__hip_bfloat16*)((char*)d_ws + permoff);

    hipMemsetAsync(bcount, 0, (size_t)nb * sizeof(int), stream);

    int block = 256;
    int egrid = (n_edges + block - 1) / block;
    bucket_hist_kernel<<<egrid, block, 0, stream>>>(eidx, bcount, n_edges);
    bucket_scan_kernel<<<1, 1024, 0, stream>>>(bcount, boffset, bcursor, nb);
    bucket_scatter_kernel<<<2048, 256, 0, stream>>>(
        msgs, eidx, cutoff, bcursor, tgt_arr, perm, n_edges);
    bucket_reduce_linear_kernel<<<nb, 256, 0, stream>>>(
        perm, tgt_arr, boffset, W0, W1, W2, (float*)d_out, n_nodes);
}

// Round 8
// 205.534 us; speedup vs baseline: 3.1691x; 3.1691x over previous
//
#include <hip/hip_runtime.h>

#define IRREPS 240
#define WPB 4          // waves per block
#define NPB 8          // nodes per block (2 per wave)

typedef float floatx4 __attribute__((ext_vector_type(4)));

// ---------- CSR build ----------
__global__ void histogram_kernel(const int* __restrict__ eidx, int* __restrict__ counts,
                                 int n_edges) {
    int e = blockIdx.x * blockDim.x + threadIdx.x;
    if (e >= n_edges) return;
    int2 p = reinterpret_cast<const int2*>(eidx)[e];
    atomicAdd(&counts[p.y], 1);
}

__global__ void scan_kernel(const int* __restrict__ counts, int* __restrict__ offsets,
                            int* __restrict__ cursor, int n) {
    __shared__ int part[1024];
    int t = threadIdx.x;
    int per = (n + 1023) / 1024;
    int start = t * per;
    int end = min(start + per, n);
    int sum = 0;
    for (int i = start; i < end; ++i) sum += counts[i];
    part[t] = sum;
    __syncthreads();
    for (int off = 1; off < 1024; off <<= 1) {
        int v = (t >= off) ? part[t - off] : 0;
        __syncthreads();
        part[t] += v;
        __syncthreads();
    }
    int run = (t == 0) ? 0 : part[t - 1];
    for (int i = start; i < end; ++i) {
        offsets[i] = run;
        cursor[i] = run;
        run += counts[i];
    }
}

// fill CSR with (edge_id, cutoff_bits) pairs so the gather never touches cutoff[]
__global__ void fill_pairs_kernel(const int* __restrict__ eidx,
                                  const float* __restrict__ cutoff,
                                  int* __restrict__ cursor,
                                  int2* __restrict__ pairs, int n_edges) {
    int e = blockIdx.x * blockDim.x + threadIdx.x;
    if (e >= n_edges) return;
    int2 p = reinterpret_cast<const int2*>(eidx)[e];
    float w = cutoff[e];
    int pos = atomicAdd(&cursor[p.y], 1);
    pairs[pos] = make_int2(e, __float_as_int(w));
}

// ---------- fused gather + equivariant linear ----------
// Block = 256 = 4 waves. Wave w owns nodes blockIdx*8+w and blockIdx*8+w+4:
// two independent gather streams per wave for doubled load-level parallelism.
// msgs rows are read nontemporally (single-use data).
__global__ void gather_linear_kernel(const float* __restrict__ msgs,
                                     const int2* __restrict__ pairs,
                                     const int* __restrict__ offsets,
                                     const int* __restrict__ counts,
                                     const float* __restrict__ W0,
                                     const float* __restrict__ W1,
                                     const float* __restrict__ W2,
                                     float* __restrict__ out,
                                     int n_nodes) {
    __shared__ float s_node[NPB][IRREPS];

    int t = threadIdx.x;
    int w = t >> 6;
    int lane = t & 63;

    int n0 = blockIdx.x * NPB + w;
    int n1 = n0 + WPB;

    int b0 = 0, c0 = 0, b1 = 0, c1 = 0;
    if (n0 < n_nodes) { b0 = offsets[n0]; c0 = counts[n0]; }
    if (n1 < n_nodes) { b1 = offsets[n1]; c1 = counts[n1]; }

    const floatx4* mp = reinterpret_cast<const floatx4*>(msgs);
    floatx4 a0 = (floatx4)(0.f);
    floatx4 a1 = (floatx4)(0.f);

    int jm = max(c0, c1);
    #pragma unroll 4
    for (int j = 0; j < jm; ++j) {
        if (j < c0) {
            int2 pr = pairs[b0 + j];          // wave-uniform broadcast load
            if (lane < 60) {
                floatx4 m = __builtin_nontemporal_load(&mp[(size_t)pr.x * 60 + lane]);
                float wt = __int_as_float(pr.y);
                a0 += m * wt;
            }
        }
        if (j < c1) {
            int2 pr = pairs[b1 + j];
            if (lane < 60) {
                floatx4 m = __builtin_nontemporal_load(&mp[(size_t)pr.x * 60 + lane]);
                float wt = __int_as_float(pr.y);
                a1 += m * wt;
            }
        }
    }

    if (lane < 60) {
        *reinterpret_cast<floatx4*>(&s_node[w][lane * 4]) = a0;
        *reinterpret_cast<floatx4*>(&s_node[w + WPB][lane * 4]) = a1;
    }
    __syncthreads();

    // linear phase: NPB rounds, whole block per node
    for (int j = 0; j < NPB; ++j) {
        int nd = blockIdx.x * NPB + j;
        if (nd >= n_nodes) break;
        if (t < IRREPS) {
            const float* s = s_node[j];
            float a = 0.f;
            float res;
            if (t < 64) {
                int o = t;
                #pragma unroll 8
                for (int i = 0; i < 64; ++i) a += W0[o * 64 + i] * s[i];
                res = a * 0.125f;               // 1/sqrt(64)
            } else if (t < 160) {
                int rel = t - 64;
                int o = rel / 3, d = rel - o * 3;
                #pragma unroll 8
                for (int i = 0; i < 32; ++i) a += W1[o * 32 + i] * s[64 + i * 3 + d];
                res = a * 0.17677669529663687f; // 1/sqrt(32)
            } else {
                int rel = t - 160;
                int o = rel / 5, d = rel - o * 5;
                #pragma unroll
                for (int i = 0; i < 16; ++i) a += W2[o * 16 + i] * s[160 + i * 5 + d];
                res = a * 0.25f;                // 1/sqrt(16)
            }
            out[(size_t)nd * IRREPS + t] = res;
        }
    }
}

extern "C" void kernel_launch(void* const* d_in, const int* in_sizes, int n_in,
                              void* d_out, int out_size, void* d_ws, size_t ws_size,
                              hipStream_t stream) {
    const float* msgs   = (const float*)d_in[0];
    const int*   eidx   = (const int*)d_in[1];
    const float* cutoff = (const float*)d_in[2];
    const float* W0     = (const float*)d_in[3];
    const float* W1     = (const float*)d_in[4];
    const float* W2     = (const float*)d_in[5];

    int n_edges = in_sizes[0] / IRREPS;
    int n_nodes = out_size / IRREPS;

    int*  counts  = (int*)d_ws;
    int*  offsets = counts + n_nodes;
    int*  cursor  = offsets + n_nodes;
    int2* pairs   = (int2*)(cursor + n_nodes);

    (void)hipMemsetAsync(counts, 0, (size_t)n_nodes * sizeof(int), stream);

    int block = 256;
    int egrid = (n_edges + block - 1) / block;
    histogram_kernel<<<egrid, block, 0, stream>>>(eidx, counts, n_edges);
    scan_kernel<<<1, 1024, 0, stream>>>(counts, offsets, cursor, n_nodes);
    fill_pairs_kernel<<<egrid, block, 0, stream>>>(eidx, cutoff, cursor, pairs, n_edges);

    int ngrid = (n_nodes + NPB - 1) / NPB;
    gather_linear_kernel<<<ngrid, 256, 0, stream>>>(
        msgs, pairs, offsets, counts, W0, W1, W2, (float*)d_out, n_nodes);
}